// Round 14
// baseline (578.750 us; speedup 1.0000x reference)
//
#include <hip/hip_runtime.h>
#include <hip/hip_bf16.h>

// LightGCN on MI355X: 3x SpMM + running sum. N=150000, DIM=64, NNZ=4M.
// R5:  fill_k 281us (random 4B scatter, 370MB write churn).
// R7:  int2 pack: WRITE->247MB but dur FLAT -> random-line-op bound.
// R9:  586-counter passB: 6830-deep contended atomic chains = 1102us.
// R10: LDS multisplit: 840us. pass1 grid-starved (5% occ).
// R11: pass1 CHUNK->8192; spmm unroll 4->8: 190->135us (latency-bound).
// R12: spmm 2 rows/wave + packed-uint: 135->93us. HBM-path 41%, VALU 38%,
//      occ 74% -> nothing saturated; ~9 B/cyc/CU gather ~ MSHR floor?
// R13: (1) spmm unroll 16 (discriminator: helps -> still ILP-bound;
//          flat -> request-queue floor, spmm done);
//      (2) buckets 512->256 rows: passC 293->586 blocks (was 1.14/CU
//          straggler-bound);
//      (3) init folded into bhist (both BW-light grid-striders).

#define NUSERS 100000
#define NITEMS 50000
#define NNODES 150000
#define DIM    64
#define NNZ_E  4000000
#define BSH    8                          // bucket = row >> 8 (256 rows)
#define NBKT   ((NNODES + 255) / 256)     // 586
#define CHUNK  8192                       // edges per pass1 block
#define NB1    ((NNZ_E + CHUNK - 1) / CHUNK)  // 489

__device__ inline unsigned short f2b(float f) {
    __hip_bfloat16 h = __float2bfloat16(f);
    return *reinterpret_cast<unsigned short*>(&h);
}
__device__ inline float b2f(unsigned short b) {
    return __uint_as_float((unsigned)b << 16);
}

// ---- bucket histogram (LDS-aggregated) + fused dense init ---------------

__global__ void bhist_k(const int* __restrict__ rows, int* __restrict__ bcnt,
                        const float4* __restrict__ ue, const float4* __restrict__ ie,
                        ushort4* __restrict__ h0, float4* __restrict__ esum) {
    __shared__ int cnt[NBKT];
    for (int i = threadIdx.x; i < NBKT; i += 256) cnt[i] = 0;
    __syncthreads();
    int stride = gridDim.x * 256;
    int tid = blockIdx.x * 256 + threadIdx.x;
    for (int i = tid; i < NNZ_E; i += stride)
        atomicAdd(&cnt[rows[i] >> BSH], 1);

    // fused dense init: h0(bf16) = all_emb; esum(fp32, = d_out) = all_emb
    const int NU4 = NUSERS * (DIM / 4);
    const int NT4 = NNODES * (DIM / 4);
    for (int i = tid; i < NT4; i += stride) {
        float4 v = (i < NU4) ? ue[i] : ie[i - NU4];
        esum[i] = v;
        ushort4 b;
        b.x = f2b(v.x); b.y = f2b(v.y); b.z = f2b(v.z); b.w = f2b(v.w);
        h0[i] = b;
    }

    __syncthreads();
    for (int i = threadIdx.x; i < NBKT; i += 256)
        if (cnt[i]) atomicAdd(&bcnt[i], cnt[i]);
}

// ---- exclusive scan of 586 bucket counts (1 block of 1024) --------------

__global__ void __launch_bounds__(1024) bscan_k(const int* __restrict__ bcnt,
                        int* __restrict__ bbase, int* __restrict__ bcur,
                        int* __restrict__ rs) {
    __shared__ int s[1024];
    int t = threadIdx.x;
    int v = (t < NBKT) ? bcnt[t] : 0;
    s[t] = v;
    __syncthreads();
    for (int off = 1; off < 1024; off <<= 1) {
        int add = (t >= off) ? s[t - off] : 0;
        __syncthreads();
        s[t] += add;
        __syncthreads();
    }
    if (t < NBKT) {
        int ex = s[t] - v;
        bbase[t] = ex;
        bcur[t]  = ex;
    }
    if (t == 0) {
        bbase[NBKT] = NNZ_E;
        rs[NNODES]  = NNZ_E;
    }
}

// ---- pass1: multisplit scatter into bucket-grouped ebuf -----------------
// pack: col bits 0..17, localrow (row&255) bits 18..25.

__global__ void pass1_k(const int* __restrict__ rows, const int* __restrict__ cols,
                        const float* __restrict__ vals, int* __restrict__ bcur,
                        int2* __restrict__ ebuf) {
    __shared__ int lcnt[NBKT];
    __shared__ int lcur[NBKT];
    int base = blockIdx.x * CHUNK;
    int end  = min(base + CHUNK, NNZ_E);
    for (int i = threadIdx.x; i < NBKT; i += 256) lcnt[i] = 0;
    __syncthreads();
    for (int i = base + threadIdx.x; i < end; i += 256)
        atomicAdd(&lcnt[rows[i] >> BSH], 1);
    __syncthreads();
    for (int i = threadIdx.x; i < NBKT; i += 256)
        lcur[i] = lcnt[i] ? atomicAdd(&bcur[i], lcnt[i]) : 0;
    __syncthreads();
    for (int i = base + threadIdx.x; i < end; i += 256) {
        int r = rows[i];
        int p = atomicAdd(&lcur[r >> BSH], 1);
        ebuf[p] = make_int2(cols[i] | ((r & 255) << 18), __float_as_int(vals[i]));
    }
}

// ---- passC: per-bucket LDS ranking -> exact CSR slots + rs --------------
// 256 rows/bucket, 586 blocks (2.3/CU: no straggler tail).

__global__ void passC_k(const int* __restrict__ bbase, const int2* __restrict__ ebuf,
                        int* __restrict__ rs, int2* __restrict__ cedge) {
    __shared__ int rcnt[256];
    __shared__ int s[256];
    int b  = blockIdx.x;
    int t  = threadIdx.x;
    int s0 = bbase[b], e0 = bbase[b + 1];
    int rows0 = b << BSH;
    int nrows = min(256, NNODES - rows0);

    rcnt[t] = 0;
    __syncthreads();
    for (int j = s0 + t; j < e0; j += 256)
        atomicAdd(&rcnt[(unsigned)ebuf[j].x >> 18], 1);
    __syncthreads();

    int v = rcnt[t];
    s[t] = v;
    __syncthreads();
    for (int off = 1; off < 256; off <<= 1) {
        int add = (t >= off) ? s[t - off] : 0;
        __syncthreads();
        s[t] += add;
        __syncthreads();
    }
    int ex = s[t] - v;                    // exclusive scan
    if (t < nrows) rs[rows0 + t] = s0 + ex;
    __syncthreads();
    rcnt[t] = ex;                         // running cursor
    __syncthreads();

    for (int j = s0 + t; j < e0; j += 256) {
        int2 ee = ebuf[j];
        int lr  = (unsigned)ee.x >> 18;
        int pos = s0 + atomicAdd(&rcnt[lr], 1);
        cedge[pos] = make_int2(ee.x & 0x3FFFF, ee.y);
    }
}

// ---- SpMM: 2 rows per wave; lane = (half, dim-pair); uint gathers -------
// 16-deep unroll -> 32 gathers in flight/wave; ladder 16 -> 8 -> scalar.

template <int FINAL>
__global__ void spmm_k(const int* __restrict__ rs, const int2* __restrict__ cedge,
                       const unsigned short* __restrict__ x,
                       unsigned short* __restrict__ hout, float* __restrict__ esum) {
    int pair = (blockIdx.x * blockDim.x + threadIdx.x) >> 6;  // wave id
    int lane = threadIdx.x & 63;
    int half = lane >> 5;
    int m    = lane & 31;                 // dim-pair: dims 2m, 2m+1
    int row  = pair * 2 + half;
    if (row >= NNODES) return;
    int s = rs[row], e = rs[row + 1];
    const char* xb = (const char*)x;

    float acc0 = 0.f, acc1 = 0.f;
    int j = s;
    for (; j + 16 <= e; j += 16) {
        int2 ee[16];
        unsigned u[16];
        #pragma unroll
        for (int k = 0; k < 16; ++k) ee[k] = cedge[j + k];
        #pragma unroll
        for (int k = 0; k < 16; ++k)
            u[k] = *(const unsigned*)(xb + ((size_t)ee[k].x << 7) + (m << 2));
        #pragma unroll
        for (int k = 0; k < 16; ++k) {
            float v = __int_as_float(ee[k].y);
            acc0 = fmaf(v, __uint_as_float(u[k] << 16), acc0);
            acc1 = fmaf(v, __uint_as_float(u[k] & 0xffff0000u), acc1);
        }
    }
    if (j + 8 <= e) {
        int2 ee[8];
        unsigned u[8];
        #pragma unroll
        for (int k = 0; k < 8; ++k) ee[k] = cedge[j + k];
        #pragma unroll
        for (int k = 0; k < 8; ++k)
            u[k] = *(const unsigned*)(xb + ((size_t)ee[k].x << 7) + (m << 2));
        #pragma unroll
        for (int k = 0; k < 8; ++k) {
            float v = __int_as_float(ee[k].y);
            acc0 = fmaf(v, __uint_as_float(u[k] << 16), acc0);
            acc1 = fmaf(v, __uint_as_float(u[k] & 0xffff0000u), acc1);
        }
        j += 8;
    }
    for (; j < e; ++j) {
        int2 ee = cedge[j];
        unsigned uu = *(const unsigned*)(xb + ((size_t)ee.x << 7) + (m << 2));
        float v = __int_as_float(ee.y);
        acc0 = fmaf(v, __uint_as_float(uu << 16), acc0);
        acc1 = fmaf(v, __uint_as_float(uu & 0xffff0000u), acc1);
    }

    int o2 = row * 32 + m;                        // float2 / uint index
    float2 rv = ((const float2*)esum)[o2];
    float r0 = rv.x + acc0, r1 = rv.y + acc1;
    if (FINAL) {
        ((float2*)esum)[o2] = make_float2(r0 * 0.25f, r1 * 0.25f);
    } else {
        ((float2*)esum)[o2] = make_float2(r0, r1);
        ((unsigned*)hout)[o2] = ((unsigned)f2b(acc1) << 16) | f2b(acc0);
    }
}

// ---- launch -------------------------------------------------------------

extern "C" void kernel_launch(void* const* d_in, const int* in_sizes, int n_in,
                              void* d_out, int out_size, void* d_ws, size_t ws_size,
                              hipStream_t stream) {
    const float* ue   = (const float*)d_in[0];
    const float* ie   = (const float*)d_in[1];
    const float* vals = (const float*)d_in[2];
    const int*   rows = (const int*)d_in[3];
    const int*   cols = (const int*)d_in[4];
    float*       out  = (float*)d_out;

    char*  ws  = (char*)d_ws;
    size_t off = 0;
    auto alloc = [&](size_t bytes) -> char* {
        char* p = ws + off;
        off += (bytes + 255) & ~size_t(255);
        return p;
    };
    unsigned short* h0 = (unsigned short*)alloc((size_t)NNODES * DIM * 2);  // 19.2 MB
    unsigned short* h1 = (unsigned short*)alloc((size_t)NNODES * DIM * 2);  // 19.2 MB
    int2*  cedge  = (int2*)alloc((size_t)NNZ_E * 8);                        // 32 MB
    int2*  ebuf   = (int2*)alloc((size_t)NNZ_E * 8);                        // 32 MB
    int*   rs     = (int*)alloc((size_t)(NNODES + 1) * 4);
    int*   bcnt   = (int*)alloc((size_t)(NBKT + 1) * 4);
    int*   bbase  = (int*)alloc((size_t)(NBKT + 1) * 4);
    int*   bcur   = (int*)alloc((size_t)(NBKT + 1) * 4);
    (void)in_sizes; (void)n_in; (void)out_size;

    if (ws_size < off) return;   // clean absmax fail, not OOB fault

    // CSR build: LDS-aggregated multisplit (+ fused dense init in bhist)
    hipMemsetAsync(bcnt, 0, (size_t)(NBKT + 1) * 4, stream);
    bhist_k<<<256, 256, 0, stream>>>(rows, bcnt, (const float4*)ue,
                                     (const float4*)ie, (ushort4*)h0, (float4*)out);
    bscan_k<<<1, 1024, 0, stream>>>(bcnt, bbase, bcur, rs);
    pass1_k<<<NB1, 256, 0, stream>>>(rows, cols, vals, bcur, ebuf);
    passC_k<<<NBKT, 256, 0, stream>>>(bbase, ebuf, rs, cedge);

    // 3 propagation layers, emb_sum fused; last fuses /4
    const int SG = (NNODES / 2) * 64 / 256;   // 18750 blocks
    spmm_k<0><<<SG, 256, 0, stream>>>(rs, cedge, h0, h1, out);
    spmm_k<0><<<SG, 256, 0, stream>>>(rs, cedge, h1, h0, out);
    spmm_k<1><<<SG, 256, 0, stream>>>(rs, cedge, h0, h1, out);
}